// Round 7
// baseline (261.828 us; speedup 1.0000x reference)
//
#include <hip/hip_runtime.h>
#include <hip/hip_bf16.h>

#define BB 4
#define SS 2048
#define DM 1024
#define DN 64

typedef short short8 __attribute__((ext_vector_type(8)));
typedef float f32x4 __attribute__((ext_vector_type(4)));
typedef unsigned short ushort;

__device__ __forceinline__ ushort f2bf(float f) {
    union { float f; unsigned u; } v; v.f = f;
    unsigned r = v.u + 0x7fffu + ((v.u >> 16) & 1u);
    return (ushort)(r >> 16);
}
__device__ __forceinline__ float bf2f(ushort h) {
    union { unsigned u; float f; } v; v.u = ((unsigned)h) << 16; return v.f;
}
__device__ __forceinline__ short8 cvt8(float4 a, float4 b) {
    ushort t[8] = { f2bf(a.x), f2bf(a.y), f2bf(a.z), f2bf(a.w),
                    f2bf(b.x), f2bf(b.y), f2bf(b.z), f2bf(b.w) };
    return *(short8*)t;
}

// ---------------------------------------------------------------------------
// proj: out = x @ w^T + b. KEY CHANGE: weights live in LDS (staged per 256-K
// chunk, fp32->bf16 cvt at stage time) so the inner K-loop's B-side is
// ds_read_b128 (no global-latency chain per MFMA). A-side: 4-deep register
// pipeline of fp32 row loads + in-loop cvt. Block = 32 rows x 64 cols,
// 4 waves (rg = wv&1: 16-row group, nh = wv>>1: 32-col half). Grid 768.
// qp/kp row-major bf16 [8192][64]; vp transposed [4][64][2048].
// ---------------------------------------------------------------------------
__global__ __launch_bounds__(256, 3) void proj_kernel(
    const float* __restrict__ q, const float* __restrict__ k, const float* __restrict__ v,
    const float* __restrict__ wq, const float* __restrict__ wk, const float* __restrict__ wvm,
    const float* __restrict__ bq, const float* __restrict__ bk, const float* __restrict__ bvp,
    ushort* __restrict__ qp, ushort* __restrict__ kp, ushort* __restrict__ vpT)
{
    __shared__ __align__(16) ushort B_lds[64][264];   // 33.8 KB; 528B row stride

    const int tid  = threadIdx.x;
    const int proj = blockIdx.y;
    const int m0   = blockIdx.x * 32;

    const float* x    = (proj == 0) ? q  : (proj == 1) ? k  : v;
    const float* wm   = (proj == 0) ? wq : (proj == 1) ? wk : wvm;
    const float* bias = (proj == 0) ? bq : (proj == 1) ? bk : bvp;

    const int wv   = tid >> 6;
    const int lane = tid & 63;
    const int l16  = lane & 15;
    const int quad = lane >> 4;
    const int rg   = wv & 1;     // 16-row group
    const int nh   = wv >> 1;    // 32-col half

    const float* arow = x + (size_t)(m0 + rg * 16 + l16) * DM + quad * 8;

    // A register pipeline: 4 K-steps deep (step = 32 K)
    float4 apf[4][2];
#pragma unroll
    for (int s = 0; s < 4; s++) {
        apf[s][0] = *(const float4*)(arow + s * 32);
        apf[s][1] = *(const float4*)(arow + s * 32 + 4);
    }

    f32x4 acc[2];
    acc[0] = (f32x4){0.f, 0.f, 0.f, 0.f};
    acc[1] = (f32x4){0.f, 0.f, 0.f, 0.f};

    for (int c = 0; c < 4; c++) {               // K-chunks of 256
        __syncthreads();                        // prior chunk's B reads done
        // stage B chunk: 64 rows x 256 cols fp32 -> bf16 LDS (cvt once here)
#pragma unroll
        for (int j = 0; j < 16; j++) {
            int u   = tid + j * 256;            // 4096 float4 units
            int row = u >> 6, c4 = u & 63;
            float4 f = *(const float4*)(wm + (size_t)row * DM + c * 256 + c4 * 4);
            ushort t4[4] = { f2bf(f.x), f2bf(f.y), f2bf(f.z), f2bf(f.w) };
            *(unsigned long long*)&B_lds[row][c4 * 4] = *(unsigned long long*)t4;
        }
        __syncthreads();

#pragma unroll
        for (int kk = 0; kk < 8; kk++) {        // 8 x 32-K steps
            const int step = c * 8 + kk;
            const int ai   = step & 3;
            short8 a = cvt8(apf[ai][0], apf[ai][1]);
            if (step + 4 < 32) {                // refill pipeline slot
                apf[ai][0] = *(const float4*)(arow + (step + 4) * 32);
                apf[ai][1] = *(const float4*)(arow + (step + 4) * 32 + 4);
            }
#pragma unroll
            for (int tt = 0; tt < 2; tt++) {
                const int t = nh * 2 + tt;
                short8 b = *(const short8*)&B_lds[t * 16 + l16][kk * 32 + quad * 8];
                acc[tt] = __builtin_amdgcn_mfma_f32_16x16x32_bf16(a, b, acc[tt], 0, 0, 0);
            }
        }
    }

    // epilogue: C/D layout col = t*16+l16, row = quad*4+r
#pragma unroll
    for (int tt = 0; tt < 2; tt++) {
        const int n = (nh * 2 + tt) * 16 + l16;
        float bb_ = bias[n];
#pragma unroll
        for (int r = 0; r < 4; r++) {
            int grow = m0 + rg * 16 + quad * 4 + r;
            ushort h = f2bf(acc[tt][r] + bb_);
            if (proj == 0)      qp[(size_t)grow * DN + n] = h;
            else if (proj == 1) kp[(size_t)grow * DN + n] = h;
            else {
                int bb = grow >> 11, ss = grow & 2047;
                vpT[((size_t)bb * DN + n) * SS + ss] = h;
            }
        }
    }
}

// ---------------------------------------------------------------------------
// flash: r5 geometry (1024 blocks x 4 waves, 8 key-slices of 256) with the
// softmax dependent chains cut: (1) max-reduce shfls BATCHED across the 4
// rows (4 dependent levels total, not 16); (2) NO sum-reduce — l accumulated
// by 2 extra MFMAs vs an all-ones B fragment (same alpha recurrence as O).
// Mask fp32 direct loads, double-buffered; K frags double-buffered.
// ---------------------------------------------------------------------------
template<int KPS>
__global__ __launch_bounds__(256, 2) void flash_kernel(
    const float* __restrict__ mask,
    const ushort* __restrict__ qp,
    const ushort* __restrict__ kp,
    const ushort* __restrict__ vpT,
    ushort* __restrict__ part_O,    // [split][8192][64] bf16
    float* __restrict__ part_ml)    // [split][8192][2]
{
    constexpr int NSLICE = SS / KPS;
    constexpr int NIT    = KPS / 64;

    __shared__ __align__(16) ushort p_lds[4][16][72];

    const int tid  = threadIdx.x;
    const int wv   = tid >> 6;
    const int lane = tid & 63;
    const int l16  = lane & 15;
    const int quad = lane >> 4;

    const int gw    = blockIdx.x * 4 + wv;
    const int qg    = gw & 127;
    const int rest  = gw >> 7;
    const int slice = rest % NSLICE;
    const int b     = rest / NSLICE;

    const ushort* qbase = qp + ((size_t)b * SS + qg * 16 + l16) * DN + quad * 8;
    short8 aq0 = *(const short8*)(qbase);
    short8 aq1 = *(const short8*)(qbase + 32);

    // all-ones bf16 B fragment for the l-accumulating MFMA
    ushort onev[8] = { 0x3F80, 0x3F80, 0x3F80, 0x3F80, 0x3F80, 0x3F80, 0x3F80, 0x3F80 };
    short8 bone = *(short8*)onev;

    float m_r[4] = { -__builtin_inff(), -__builtin_inff(),
                     -__builtin_inff(), -__builtin_inff() };
    f32x4 Oacc[4], Lacc;
#pragma unroll
    for (int t = 0; t < 4; t++) Oacc[t] = (f32x4){0.f, 0.f, 0.f, 0.f};
    Lacc = (f32x4){0.f, 0.f, 0.f, 0.f};

    const size_t mrow0 = ((size_t)b * SS + qg * 16 + quad * 4) * SS;
    const int k_begin = slice * KPS;

    float  mk[2][4][4];
    short8 bk0[2][4], bk1[2][4];

    auto load_tile = [&](int buf, int k0) {
#pragma unroll
        for (int t = 0; t < 4; t++) {
            const ushort* kb_ = kp + ((size_t)b * SS + k0 + t * 16 + l16) * DN + quad * 8;
            bk0[buf][t] = *(const short8*)(kb_);
            bk1[buf][t] = *(const short8*)(kb_ + 32);
        }
#pragma unroll
        for (int t = 0; t < 4; t++)
#pragma unroll
            for (int r = 0; r < 4; r++)
                mk[buf][t][r] = mask[mrow0 + (size_t)r * SS + k0 + t * 16 + l16];
    };

    load_tile(0, k_begin);

#pragma unroll
    for (int it = 0; it < NIT; ++it) {
        const int cur = it & 1;
        const int k0  = k_begin + it * 64;

        if (it + 1 < NIT) load_tile(cur ^ 1, k0 + 64);

        short8 bv0[4], bv1[4];
#pragma unroll
        for (int tf = 0; tf < 4; tf++) {
            const ushort* p_ = vpT + ((size_t)b * DN + tf * 16 + l16) * SS + k0 + quad * 8;
            bv0[tf] = *(const short8*)p_;
            bv1[tf] = *(const short8*)(p_ + 32);
        }

        // S = qp . kp^T (C layout: key = t*16+l16, qrow = quad*4+r)
        f32x4 sc[4];
#pragma unroll
        for (int t = 0; t < 4; t++) {
            f32x4 z = (f32x4){0.f, 0.f, 0.f, 0.f};
            z = __builtin_amdgcn_mfma_f32_16x16x32_bf16(aq0, bk0[cur][t], z, 0, 0, 0);
            z = __builtin_amdgcn_mfma_f32_16x16x32_bf16(aq1, bk1[cur][t], z, 0, 0, 0);
            sc[t] = z;
        }

        // scores + BATCHED 16-lane max reduction (4 dependent levels total)
        float s[4][4], tmax[4];
#pragma unroll
        for (int r = 0; r < 4; r++) tmax[r] = -__builtin_inff();
#pragma unroll
        for (int t = 0; t < 4; t++)
#pragma unroll
            for (int r = 0; r < 4; r++) {
                s[t][r] = sc[t][r] * 0.125f - 1e9f * mk[cur][t][r];
                tmax[r] = fmaxf(tmax[r], s[t][r]);
            }
#pragma unroll
        for (int off = 8; off >= 1; off >>= 1)
#pragma unroll
            for (int r = 0; r < 4; r++)
                tmax[r] = fmaxf(tmax[r], __shfl_xor(tmax[r], off, 16));

        float alpha[4];
#pragma unroll
        for (int r = 0; r < 4; r++) {
            float mnew = fmaxf(m_r[r], tmax[r]);
            alpha[r] = __expf(m_r[r] - mnew);
            m_r[r] = mnew;
        }
#pragma unroll
        for (int t = 0; t < 4; t++)
#pragma unroll
            for (int r = 0; r < 4; r++)
                p_lds[wv][quad * 4 + r][t * 16 + l16] = f2bf(__expf(s[t][r] - m_r[r]));
#pragma unroll
        for (int tf = 0; tf < 4; tf++)
#pragma unroll
            for (int r = 0; r < 4; r++)
                Oacc[tf][r] *= alpha[r];
#pragma unroll
        for (int r = 0; r < 4; r++) Lacc[r] *= alpha[r];

        // P: C-layout -> A-layout via wave-private LDS (in-order DS pipe)
        short8 ap0 = *(const short8*)&p_lds[wv][l16][quad * 8];
        short8 ap1 = *(const short8*)&p_lds[wv][l16][32 + quad * 8];
#pragma unroll
        for (int tf = 0; tf < 4; tf++) {
            Oacc[tf] = __builtin_amdgcn_mfma_f32_16x16x32_bf16(ap0, bv0[tf], Oacc[tf], 0, 0, 0);
            Oacc[tf] = __builtin_amdgcn_mfma_f32_16x16x32_bf16(ap1, bv1[tf], Oacc[tf], 0, 0, 0);
        }
        // l = P @ ones : row-sum via MFMA (replaces the shfl sum-reduce)
        Lacc = __builtin_amdgcn_mfma_f32_16x16x32_bf16(ap0, bone, Lacc, 0, 0, 0);
        Lacc = __builtin_amdgcn_mfma_f32_16x16x32_bf16(ap1, bone, Lacc, 0, 0, 0);
    }

    const int rowg = (b * SS + qg * 16) + quad * 4;
#pragma unroll
    for (int r = 0; r < 4; r++) {
        size_t row = (size_t)rowg + r;
        if (l16 == 0) {
            part_ml[((size_t)slice * (BB * SS) + row) * 2 + 0] = m_r[r];
            part_ml[((size_t)slice * (BB * SS) + row) * 2 + 1] = Lacc[r];
        }
#pragma unroll
        for (int tf = 0; tf < 4; tf++)
            part_O[((size_t)slice * (BB * SS) + row) * DN + tf * 16 + l16] =
                f2bf(Oacc[tf][r]);
    }
}

// ---------------------------------------------------------------------------
// combine: merge nslice partials per row; normalize.
// ---------------------------------------------------------------------------
__global__ __launch_bounds__(256) void combine_kernel(
    const ushort* __restrict__ part_O, const float* __restrict__ part_ml,
    float* __restrict__ out, int nslice)
{
    const int tid = threadIdx.x;
    const int row = blockIdx.x * 4 + (tid >> 6);
    const int f   = tid & 63;

    float ms[8], ls[8];
    float M = -__builtin_inff();
    for (int i = 0; i < nslice; i++) {
        ms[i] = part_ml[((size_t)i * (BB * SS) + row) * 2 + 0];
        ls[i] = part_ml[((size_t)i * (BB * SS) + row) * 2 + 1];
        M = fmaxf(M, ms[i]);
    }
    float L = 0.f, acc = 0.f;
    for (int i = 0; i < nslice; i++) {
        float e = __expf(ms[i] - M);
        L += e * ls[i];
        acc += e * bf2f(part_O[((size_t)i * (BB * SS) + row) * DN + f]);
    }
    out[(size_t)row * DN + f] = acc / L;
}

extern "C" void kernel_launch(void* const* d_in, const int* in_sizes, int n_in,
                              void* d_out, int out_size, void* d_ws, size_t ws_size,
                              hipStream_t stream) {
    const float* q    = (const float*)d_in[0];
    const float* k    = (const float*)d_in[1];
    const float* v    = (const float*)d_in[2];
    const float* mask = (const float*)d_in[3];
    const float* wq   = (const float*)d_in[4];
    const float* bq   = (const float*)d_in[5];
    const float* wk   = (const float*)d_in[6];
    const float* bk   = (const float*)d_in[7];
    const float* wv   = (const float*)d_in[8];
    const float* bv   = (const float*)d_in[9];
    float* out = (float*)d_out;

    char* p = (char*)d_ws;
    ushort* qp  = (ushort*)p;   p += (size_t)BB * SS * DN * 2;   // 1 MB
    ushort* kp  = (ushort*)p;   p += (size_t)BB * SS * DN * 2;   // 1 MB
    ushort* vpT = (ushort*)p;   p += (size_t)BB * SS * DN * 2;   // 1 MB
    size_t fixed = (size_t)(p - (char*)d_ws);

    int split = 8;
    for (;;) {
        size_t flash_bytes = (size_t)split * BB * SS * 2 * 4 + (size_t)split * BB * SS * DN * 2;
        if (split == 1 || fixed + flash_bytes <= ws_size) break;
        split >>= 1;
    }

    float*  part_ml = (float*)p;   p += (size_t)split * BB * SS * 2 * 4;
    ushort* part_O  = (ushort*)p;

    proj_kernel<<<dim3(256, 3), 256, 0, stream>>>(q, k, v, wq, wk, wv, bq, bk, bv,
                                                  qp, kp, vpT);
    switch (split) {
        case 8:  flash_kernel<256> <<<128 * 8, 256, 0, stream>>>(mask, qp, kp, vpT, part_O, part_ml); break;
        case 4:  flash_kernel<512> <<<128 * 4, 256, 0, stream>>>(mask, qp, kp, vpT, part_O, part_ml); break;
        case 2:  flash_kernel<1024><<<128 * 2, 256, 0, stream>>>(mask, qp, kp, vpT, part_O, part_ml); break;
        default: flash_kernel<2048><<<128 * 1, 256, 0, stream>>>(mask, qp, kp, vpT, part_O, part_ml); break;
    }
    combine_kernel<<<(BB * SS) / 4, 256, 0, stream>>>(part_O, part_ml, out, split);
}